// Round 12
// baseline (44.482 us; speedup 1.0000x reference)
//
#include <hip/hip_runtime.h>

// ECT: x[N,3] f32, v[3,64] f32, batch[N] int32 (sorted, 64 batches)
// out[64,64,64] f32 = cumsum over bins of per-(batch,bin,dir) histogram.
// init: zero d_out + parallel batch-boundary detection (offs[65]).
// hist: PER-WAVE u8 LDS histograms (non-atomic ds_read_u8/ds_write_b8 RMW,
// stride-68 bank spread), fused local-cumsum flush via exact f32 atomics.
#define RES 64
#define TD 64
#define NB 64
#define BLK 1024            // 16 waves per block
#define WAVES 16
#define CHUNK 2048          // points per block (flat grid: N/CHUNK blocks)
#define CSTR 68             // per-lane byte stride (odd*4 -> 32-bank 2-way free)
#define CPYB (64 * CSTR)    // 4352 B per wave copy
#define CPYW (CPYB / 4)     // 1088 dwords per wave copy

// grid: 1024 blocks x 256 threads. Each thread zeroes one float of out AND
// scans a strided slice of batch; each offs slot has exactly one writer.
__global__ __launch_bounds__(256) void ect_init_kernel(
    const int* __restrict__ batch, int N,
    float* __restrict__ out, int* __restrict__ offs)
{
    const int gid = blockIdx.x * 256 + threadIdx.x;
    out[gid] = 0.0f;                              // 262144 floats = 1 MB

    if (gid == 0) {
        int b0 = batch[0];
        for (int bb = 0; bb <= b0; ++bb) offs[bb] = 0;   // leading (empty) ids
    }
    for (int i = gid; i < N; i += 262144) {
        int b0 = batch[i];
        int b1 = (i + 1 < N) ? batch[i + 1] : NB;        // sentinel closes tail
        if (b0 != b1) {
            for (int bb = b0 + 1; bb <= b1; ++bb) offs[bb] = i + 1;  // ~63 total
        }
    }
}

__global__ __launch_bounds__(BLK) void ect_hist_kernel(
    const float* __restrict__ x, const float* __restrict__ v,
    const int* __restrict__ offs, float* __restrict__ out, int N)
{
    const int start = blockIdx.x * CHUNK;         // flat, perfectly balanced
    const int stop  = min(start + CHUNK, N);
    if (start >= N) return;

    __shared__ unsigned h8w[WAVES * CPYW];        // 69632 B: 16 u8 wave-copies
    __shared__ unsigned col_part[TD][17];         // prefix scratch (odd stride)

    const int t = threadIdx.x & 63;               // lane id = direction
    const int w = threadIdx.x >> 6;               // wave id 0..15
    // per-lane private histogram row: copy w, direction t, 68-byte stride.
    unsigned char* __restrict__ hl =
        (unsigned char*)h8w + w * CPYB + t * CSTR;
    const float S = 64.0f / 2.2f;                 // RES / (2*RADIUS)
    const float v0S = v[t] * S;
    const float v1S = v[TD + t] * S;
    const float v2S = v[2 * TD + t] * S;
    // bin = floor(x·v * S + 32), clipped to [0,63]

    // batch of first point: largest b with offs[b] <= start (uniform)
    int lo = 0, hi = NB;
    while (lo < hi) {
        int mid = (lo + hi + 1) >> 1;
        if (offs[mid] <= start) lo = mid; else hi = mid - 1;
    }
    int b = lo;

    // point j's coord k at flat tile offset q=3j+k -> register q>>6, lane q&63
    // (compile-time constants after full unroll -> v_readlane broadcast).
#define SELREG(q, r0, r1, r2) ((q) < 64 ? (r0) : ((q) < 128 ? (r1) : (r2)))
#define RD(q, r0, r1, r2) __uint_as_float(__builtin_amdgcn_readlane(           \
        __float_as_uint(SELREG(q, r0, r1, r2)), (q) & 63))
#define PROC1(j, r0, r1, r2) {                                                 \
        float x0 = RD(3*(j), r0,r1,r2), x1 = RD(3*(j)+1, r0,r1,r2),            \
              x2 = RD(3*(j)+2, r0,r1,r2);                                      \
        float f = fmaf(x0, v0S, fmaf(x1, v1S, fmaf(x2, v2S, 32.0f)));          \
        f = __builtin_amdgcn_fmed3f(f, 0.0f, 63.0f);                           \
        int bin = (int)f;                                                      \
        hl[bin] = (unsigned char)(hl[bin] + 1u); }   /* non-atomic: lane-private */

    int seg = start;
    while (seg < stop) {                          // one iter per batch segment
        while (offs[b + 1] <= seg) ++b;           // skip empty batches (uniform)
        const int segend = min(stop, offs[b + 1]);

        for (int i = threadIdx.x; i < WAVES * CPYW; i += BLK) h8w[i] = 0u;
        __syncthreads();

        const int npts = segend - seg;
        const int nf = npts >> 6;                 // full 64-point tiles
        // max per-cell count: <=2 full tiles + tail per wave = 191 < 255 (u8 ok)

        // software-pipelined full tiles: issue next tile's loads, then
        // process current tile from registers (~1300 cyc covers VMEM latency)
        float c0, c1, c2, n0, n1, n2;
        int tl = w;
        if (tl < nf) {
            const int fb = 3 * (seg + (tl << 6)) + t;
            c0 = x[fb]; c1 = x[fb + 64]; c2 = x[fb + 128];
        }
        for (; tl < nf; tl += WAVES) {
            const int tn = tl + WAVES;
            if (tn < nf) {                        // prefetch next tile (uniform)
                const int fb = 3 * (seg + (tn << 6)) + t;
                n0 = x[fb]; n1 = x[fb + 64]; n2 = x[fb + 128];
            }
            #pragma unroll
            for (int j = 0; j < 64; ++j) PROC1(j, c0, c1, c2);
            if (tn < nf) { c0 = n0; c1 = n1; c2 = n2; }
        }

        // ragged segment-tail tile (at most one), owned by wave (nf mod 16)
        const int rem = npts & 63;
        if (rem && w == (nf & (WAVES - 1))) {
            const int fb = 3 * (seg + (nf << 6)) + t;
            const int lim = 3 * segend;
            float l0 = (fb       < lim) ? x[fb]       : 0.0f;
            float l1 = (fb +  64 < lim) ? x[fb +  64] : 0.0f;
            float l2 = (fb + 128 < lim) ? x[fb + 128] : 0.0f;
            #pragma unroll
            for (int j = 0; j < 64; ++j) {
                if (j < rem) PROC1(j, l0, l1, l2);   // wave-uniform guard
            }
        }
        __syncthreads();

        // Fused flush: sum 16 u8 copies (dword-packed: 4 bins/read), local
        // cumsum over bins, then exact f32 atomics into batch b's slab.
        // Wave w's lane t handles column t, bins [4w, 4w+4).
        unsigned vals[4];
        {
            unsigned b0 = 0, b1 = 0, b2 = 0, b3 = 0;
            #pragma unroll
            for (int c = 0; c < WAVES; ++c) {
                unsigned d = h8w[c * CPYW + t * (CSTR / 4) + w];
                b0 += d & 255u; b1 += (d >> 8) & 255u;
                b2 += (d >> 16) & 255u; b3 += d >> 24;
            }
            vals[0] = b0; vals[1] = b0 + b1;
            vals[2] = vals[1] + b2; vals[3] = vals[2] + b3;
            col_part[t][w] = vals[3];             // my column-segment total
        }
        __syncthreads();
        {
            unsigned off = 0;
            for (int j = 0; j < w; ++j) off += col_part[t][j];  // uniform trip
            float* __restrict__ gb = out + b * (RES * TD) + t;
            #pragma unroll
            for (int i = 0; i < 4; ++i) {
                int r = (w << 2) + i;
                atomicAdd(gb + (r << 6), (float)(vals[i] + off)); // coalesced
            }
        }
        if (segend < stop) __syncthreads();       // before re-zeroing hist
        seg = segend;
    }
#undef PROC1
#undef RD
#undef SELREG
}

extern "C" void kernel_launch(void* const* d_in, const int* in_sizes, int n_in,
                              void* d_out, int out_size, void* d_ws, size_t ws_size,
                              hipStream_t stream) {
    const float* x = (const float*)d_in[0];          // [N,3]
    const float* v = (const float*)d_in[1];          // [3,64]
    const int* batch = (const int*)d_in[2];          // [N] int32, sorted
    const int N = in_sizes[2];
    int* offs = (int*)d_ws;                          // 65 ints of scratch

    ect_init_kernel<<<1024, 256, 0, stream>>>(batch, N, (float*)d_out, offs);

    const int nblocks = (N + CHUNK - 1) / CHUNK;     // 512 for N=1M
    ect_hist_kernel<<<nblocks, BLK, 0, stream>>>(x, v, offs, (float*)d_out, N);
}

// Round 13
// 32.904 us; speedup vs baseline: 1.3519x; 1.3519x over previous
//
#include <hip/hip_runtime.h>

// ECT: x[N,3] f32, v[3,64] f32, batch[N] int32 (sorted, 64 batches)
// out[64,64,64] f32 = cumsum over bins of per-(batch,bin,dir) histogram.
//
// Structure (proven best, R8 = 32.7 us):
//  init: zero d_out + parallel batch-boundary detection -> offs[65].
//  hist: per-block LDS histogram. Wave-wide ds_add_u32 = 1 atomic/point is
//        the structural floor (>=1M wave-ops for 64M increments; addr layout
//        hwt + bin*256B makes bank = t%32, bin-independent -> 0 conflicts;
//        measured ~15.8 cyc/op = RMW pipe floor). Fused local-cumsum flush
//        (linearity: sum_blocks cumsum(local) == cumsum(sum local)), exact
//        f32 atomics (counts < 2^24).
#define RES 64
#define TD 64
#define NB 64
#define BLK 1024            // 16 waves per block
#define WAVES 16
#define CHUNK 2048          // points per block (flat grid: N/CHUNK blocks)

// grid: 1024 blocks x 256 threads. Each thread zeroes one float of out AND
// scans a strided slice of batch; each offs slot has exactly one writer.
__global__ __launch_bounds__(256) void ect_init_kernel(
    const int* __restrict__ batch, int N,
    float* __restrict__ out, int* __restrict__ offs)
{
    const int gid = blockIdx.x * 256 + threadIdx.x;
    out[gid] = 0.0f;                              // 262144 floats = 1 MB

    if (gid == 0) {
        int b0 = batch[0];
        for (int bb = 0; bb <= b0; ++bb) offs[bb] = 0;   // leading (empty) ids
    }
    for (int i = gid; i < N; i += 262144) {
        int b0 = batch[i];
        int b1 = (i + 1 < N) ? batch[i + 1] : NB;        // sentinel closes tail
        if (b0 != b1) {
            for (int bb = b0 + 1; bb <= b1; ++bb) offs[bb] = i + 1;  // ~63 total
        }
    }
}

__global__ __launch_bounds__(BLK) void ect_hist_kernel(
    const float* __restrict__ x, const float* __restrict__ v,
    const int* __restrict__ offs, float* __restrict__ out, int N)
{
    const int start = blockIdx.x * CHUNK;         // flat, perfectly balanced
    const int stop  = min(start + CHUNK, N);
    if (start >= N) return;

    __shared__ unsigned hist[2][RES * TD];        // 32 KB, 2 blocks/CU
    __shared__ unsigned col_part[TD][17];         // prefix scratch (odd stride)

    const int t = threadIdx.x & 63;               // lane id = direction
    const int w = threadIdx.x >> 6;               // wave id 0..15
    unsigned* __restrict__ hwt = &hist[w >> 3][t];// waves 0-7 -> A, 8-15 -> B
    const float S = 64.0f / 2.2f;                 // RES / (2*RADIUS)
    const float v0S = v[t] * S;
    const float v1S = v[TD + t] * S;
    const float v2S = v[2 * TD + t] * S;
    // bin = floor(x·v * S + 32), clipped to [0,63]

    // batch of first point: largest b with offs[b] <= start (uniform)
    int lo = 0, hi = NB;
    while (lo < hi) {
        int mid = (lo + hi + 1) >> 1;
        if (offs[mid] <= start) lo = mid; else hi = mid - 1;
    }
    int b = lo;

    // point j's coord k at flat tile offset q=3j+k -> register q>>6, lane q&63
    // (compile-time constants after full unroll -> v_readlane broadcast).
#define SELREG(q, r0, r1, r2) ((q) < 64 ? (r0) : ((q) < 128 ? (r1) : (r2)))
#define RD(q, r0, r1, r2) __uint_as_float(__builtin_amdgcn_readlane(           \
        __float_as_uint(SELREG(q, r0, r1, r2)), (q) & 63))
#define PROC1(j, r0, r1, r2) {                                                 \
        float x0 = RD(3*(j), r0,r1,r2), x1 = RD(3*(j)+1, r0,r1,r2),            \
              x2 = RD(3*(j)+2, r0,r1,r2);                                      \
        float f = fmaf(x0, v0S, fmaf(x1, v1S, fmaf(x2, v2S, 32.0f)));          \
        f = __builtin_amdgcn_fmed3f(f, 0.0f, 63.0f);                           \
        int bin = (int)f;                                                      \
        atomicAdd(hwt + (bin << 6), 1u); }

    int seg = start;
    while (seg < stop) {                          // one iter per batch segment
        while (offs[b + 1] <= seg) ++b;           // skip empty batches (uniform)
        const int segend = min(stop, offs[b + 1]);

        for (int i = threadIdx.x; i < 2 * RES * TD; i += BLK) hist[0][i] = 0u;
        __syncthreads();

        const int npts = segend - seg;
        const int nf = npts >> 6;                 // full 64-point tiles

        // software-pipelined full tiles: issue next tile's loads, then
        // process current tile from registers (~1300 cyc covers VMEM latency)
        float c0, c1, c2, n0, n1, n2;
        int tl = w;
        if (tl < nf) {
            const int fb = 3 * (seg + (tl << 6)) + t;
            c0 = x[fb]; c1 = x[fb + 64]; c2 = x[fb + 128];
        }
        for (; tl < nf; tl += WAVES) {
            const int tn = tl + WAVES;
            if (tn < nf) {                        // prefetch next tile (uniform)
                const int fb = 3 * (seg + (tn << 6)) + t;
                n0 = x[fb]; n1 = x[fb + 64]; n2 = x[fb + 128];
            }
            #pragma unroll
            for (int j = 0; j < 64; ++j) PROC1(j, c0, c1, c2);
            if (tn < nf) { c0 = n0; c1 = n1; c2 = n2; }
        }

        // ragged segment-tail tile (at most one), owned by wave (nf mod 16)
        const int rem = npts & 63;
        if (rem && w == (nf & (WAVES - 1))) {
            const int fb = 3 * (seg + (nf << 6)) + t;
            const int lim = 3 * segend;
            float l0 = (fb       < lim) ? x[fb]       : 0.0f;
            float l1 = (fb +  64 < lim) ? x[fb +  64] : 0.0f;
            float l2 = (fb + 128 < lim) ? x[fb + 128] : 0.0f;
            #pragma unroll
            for (int j = 0; j < 64; ++j) {
                if (j < rem) PROC1(j, l0, l1, l2);   // wave-uniform guard
            }
        }
        __syncthreads();

        // Fused flush: local cumsum over bins, then exact f32 atomics.
        // Wave w's lane t handles column t, bins [4w, 4w+4).
        unsigned vals[4];
        {
            unsigned s = 0;
            #pragma unroll
            for (int i = 0; i < 4; ++i) {
                int r = (w << 2) + i;
                s += hist[0][(r << 6) + t] + hist[1][(r << 6) + t];
                vals[i] = s;                      // inclusive prefix of my 4
            }
            col_part[t][w] = s;                   // my column-segment total
        }
        __syncthreads();
        {
            unsigned off = 0;
            for (int j = 0; j < w; ++j) off += col_part[t][j];  // uniform trip
            float* __restrict__ gb = out + b * (RES * TD) + t;
            #pragma unroll
            for (int i = 0; i < 4; ++i) {
                int r = (w << 2) + i;
                atomicAdd(gb + (r << 6), (float)(vals[i] + off)); // coalesced
            }
        }
        if (segend < stop) __syncthreads();       // before re-zeroing hist
        seg = segend;
    }
#undef PROC1
#undef RD
#undef SELREG
}

extern "C" void kernel_launch(void* const* d_in, const int* in_sizes, int n_in,
                              void* d_out, int out_size, void* d_ws, size_t ws_size,
                              hipStream_t stream) {
    const float* x = (const float*)d_in[0];          // [N,3]
    const float* v = (const float*)d_in[1];          // [3,64]
    const int* batch = (const int*)d_in[2];          // [N] int32, sorted
    const int N = in_sizes[2];
    int* offs = (int*)d_ws;                          // 65 ints of scratch

    ect_init_kernel<<<1024, 256, 0, stream>>>(batch, N, (float*)d_out, offs);

    const int nblocks = (N + CHUNK - 1) / CHUNK;     // 512 for N=1M
    ect_hist_kernel<<<nblocks, BLK, 0, stream>>>(x, v, offs, (float*)d_out, N);
}